// Round 1
// baseline (309.908 us; speedup 1.0000x reference)
//
#include <hip/hip_runtime.h>

// EfficientAttention: N=8, C=256, H=W=128 (L=16384), HEADS=8, hc=32
// out = x + att,  att[n,h,cv,l] = sum_ck (ctx[ck,cv]/S[ck]) * softmax_ck(q)[ck,l]
// ctx[ck,cv] = sum_l exp(k[ck,l]) * v[cv,l],  S[ck] = sum_l exp(k[ck,l])
// (k logits ~N(0,0.32^2) -> exp without max-subtraction is safe)

typedef __attribute__((ext_vector_type(8))) short short8;
typedef __attribute__((ext_vector_type(4))) float f32x4;
typedef __attribute__((ext_vector_type(4))) float float4v;

#define NB     8
#define CCH    256
#define LSP    16384
#define NHEADS 8
#define HC     32

// k_qkv tiling
#define BN   128   // pixels per tile
#define NT   4     // tiles per block -> 512 pixels/block, 32 l-groups
#define CP   264   // xt/wt LDS pitch (256 + 8 pad: row stride 528B, 16B-aligned, spreads banks)
#define EP   136   // ekt/vt pitch
#define QP   132   // qt pitch (f32)

__device__ __forceinline__ unsigned short f2bf(float f) {
  union { float f; unsigned u; } v; v.f = f;
  unsigned r = v.u + 0x7fffu + ((v.u >> 16) & 1u);   // RNE
  return (unsigned short)(r >> 16);
}
__device__ __forceinline__ float bf2f(unsigned short b) {
  union { unsigned u; float f; } v; v.u = ((unsigned)b) << 16;
  return v.f;
}

// ---------------- kernel 0: weights -> bf16 (head-grouped rows [k(32); v(32); q(32)]),
// biases, zero ctx/S (required every launch: atomics accumulate) ----------------
__global__ void k_prep(const float* __restrict__ Wk, const float* __restrict__ bk,
                       const float* __restrict__ Wq, const float* __restrict__ bq,
                       const float* __restrict__ Wv, const float* __restrict__ bv,
                       unsigned short* __restrict__ Wb, float* __restrict__ bb,
                       float* __restrict__ ctx, float* __restrict__ S) {
  int idx = blockIdx.x * 256 + threadIdx.x;
  if (idx < NHEADS * 96 * CCH) {
    int c = idx & (CCH - 1);
    int row = (idx >> 8) % 96;
    int h = idx / (96 * CCH);
    int ch = h * HC;
    float val;
    if (row < HC)          val = Wk[(ch + row) * CCH + c];
    else if (row < 2 * HC) val = Wv[(ch + row - HC) * CCH + c];
    else                   val = Wq[(ch + row - 2 * HC) * CCH + c];
    Wb[idx] = f2bf(val);
  }
  if (idx < NHEADS * 96) {
    int row = idx % 96, h = idx / 96, ch = h * HC;
    float val;
    if (row < HC)          val = bk[ch + row];
    else if (row < 2 * HC) val = bv[ch + row - HC];
    else                   val = bq[ch + row - 2 * HC];
    bb[idx] = val;
  }
  if (idx < NB * NHEADS * HC * HC) ctx[idx] = 0.f;
  if (idx < NB * NHEADS * HC)      S[idx]   = 0.f;
}

// ---------------- kernel 0b: x [n][c][l] f32 -> xT [n][l][c] bf16 (tiled transpose) --------
__global__ __launch_bounds__(256)
void k_transpose(const float* __restrict__ x, unsigned short* __restrict__ xT) {
  __shared__ float tile[64][65];
  int b = blockIdx.x;
  int ct = b & 3;             // CCH/64
  int lt = (b >> 2) & 255;    // LSP/64
  int n  = b >> 10;
  int c0 = ct * 64, l0 = lt * 64;
  int t = threadIdx.x;
  int li = t & 63, cr = t >> 6;
  const float* xp = x + (size_t)n * CCH * LSP;
#pragma unroll
  for (int i = 0; i < 16; ++i) {
    int ci = cr * 16 + i;
    tile[ci][li] = xp[(size_t)(c0 + ci) * LSP + l0 + li];
  }
  __syncthreads();
  int ci2 = t & 63, lr = t >> 6;
  unsigned short* xo = xT + ((size_t)n * LSP + l0) * CCH + c0;
#pragma unroll
  for (int i = 0; i < 16; ++i) {
    int l = lr * 16 + i;
    xo[(size_t)l * CCH + ci2] = f2bf(tile[ci2][l]);
  }
}

// ---------------- kernel 1: fused QKV GEMM + streaming ctx/S + q-softmax ----------------
// grid: 8 n x 32 l-groups (512 px each); block 512 thr = 8 waves.
// GEMM per (head, tile): [96 x 256] x [256 x 128] via 16x16x32 bf16 MFMA,
// wave tile 48x32 (3x2 frags). LDS ~149KB -> 1 block/CU.
template<bool USE_XT>
__global__ __launch_bounds__(512, 1)
void k_qkv(const float* __restrict__ x, const unsigned short* __restrict__ xT,
           const unsigned short* __restrict__ Wb, const float* __restrict__ bb,
           unsigned short* __restrict__ qbuf, float* __restrict__ ctx,
           float* __restrict__ S) {
  __shared__ unsigned short xt[BN][CP];   // x^T tile: [pixel][channel]
  __shared__ unsigned short wt[96][CP];   // W head:   [row][channel]
  __shared__ unsigned short ekt[HC][EP];  // exp(k) bf16
  __shared__ unsigned short vt[HC][EP];   // v bf16
  __shared__ float          qt[HC][QP];   // q f32 (pre-softmax)

  int n  = (int)blockIdx.x >> 5;
  int lg = (int)blockIdx.x & 31;
  int l0 = lg * (BN * NT);
  int tid = threadIdx.x;
  int wid = tid >> 6, lane = tid & 63;
  int r16 = lane & 15, kg = lane >> 4;
  int rb  = (wid >> 2) * 48;     // 0 / 48
  int cbw = (wid & 3) * 32;      // 0/32/64/96

  const unsigned short* xTn = xT + (((size_t)n) << 14) * CCH;

  for (int h = 0; h < NHEADS; ++h) {
    __syncthreads();                       // prior head done reading wt
    for (int i = tid; i < 96 * CCH / 8; i += 512) {      // stage W (b128, conflict-free)
      int row = i >> 5;
      int cg = (i & 31) << 3;
      *(short8*)&wt[row][cg] = *(const short8*)&Wb[(h * 96 + row) * CCH + cg];
    }
    float bias[3][4];
#pragma unroll
    for (int m = 0; m < 3; ++m)
#pragma unroll
      for (int r = 0; r < 4; ++r)
        bias[m][r] = bb[h * 96 + rb + m * 16 + kg * 4 + r];

    f32x4 acc_ctx = {0.f, 0.f, 0.f, 0.f};
    float sk = 0.f;

    for (int t = 0; t < NT; ++t) {
      int lb = l0 + t * BN;
      __syncthreads();   // wt staged (t==0); prev tile's xt/ekt/vt/qt consumers done
      if constexpr (USE_XT) {
        for (int j = tid; j < BN * CCH / 8; j += 512) {
          int p = j >> 5, cg = (j & 31) << 3;
          *(short8*)&xt[p][cg] = *(const short8*)&xTn[((size_t)(lb + p) << 8) + cg];
        }
      } else {
        const float* xn = x + (size_t)n * CCH * LSP;
        for (int j = tid; j < BN * CCH / 4; j += 512) {
          int c = j >> 5, p4 = (j & 31) << 2;
          float4v xv = *(const float4v*)&xn[((size_t)c << 14) + lb + p4];
#pragma unroll
          for (int u = 0; u < 4; ++u) xt[p4 + u][c] = f2bf(xv[u]);
        }
      }
      __syncthreads();

      f32x4 acc[3][2];
#pragma unroll
      for (int m = 0; m < 3; ++m) { acc[m][0] = (f32x4){0,0,0,0}; acc[m][1] = (f32x4){0,0,0,0}; }
#pragma unroll
      for (int kk = 0; kk < 8; ++kk) {
        int kc = kk * 32 + kg * 8;
        short8 b0 = *(const short8*)&xt[cbw + r16][kc];
        short8 b1 = *(const short8*)&xt[cbw + 16 + r16][kc];
#pragma unroll
        for (int m = 0; m < 3; ++m) {
          short8 a = *(const short8*)&wt[rb + m * 16 + r16][kc];
          acc[m][0] = __builtin_amdgcn_mfma_f32_16x16x32_bf16(a, b0, acc[m][0], 0, 0, 0);
          acc[m][1] = __builtin_amdgcn_mfma_f32_16x16x32_bf16(a, b1, acc[m][1], 0, 0, 0);
        }
      }
      // scatter accumulators: rows 0-31 -> exp(k) bf16; 32-63 -> v bf16; 64-95 -> q f32
#pragma unroll
      for (int m = 0; m < 3; ++m) {
        int row0 = rb + m * 16 + kg * 4;
#pragma unroll
        for (int r = 0; r < 4; ++r) {
          int row = row0 + r;
#pragma unroll
          for (int nn = 0; nn < 2; ++nn) {
            float val = acc[m][nn][r] + bias[m][r];
            int col = cbw + nn * 16 + r16;
            if (row < HC)          ekt[row][col] = f2bf(__expf(val));
            else if (row < 2 * HC) vt[row - HC][col] = f2bf(val);
            else                   qt[row - 2 * HC][col] = val;
          }
        }
      }
      __syncthreads();
      // post phase (concurrent wave roles)
      if (wid < 4) {
        // ctx quadrant via MFMA: D[ck][cv] += sum_l ek[ck][l]*v[cv][l], K=BN
        int tm = wid >> 1, tn = wid & 1;
#pragma unroll
        for (int ks = 0; ks < 4; ++ks) {
          int kc = ks * 32 + kg * 8;
          short8 af = *(const short8*)&ekt[tm * 16 + r16][kc];
          short8 bf = *(const short8*)&vt[tn * 16 + r16][kc];
          acc_ctx = __builtin_amdgcn_mfma_f32_16x16x32_bf16(af, bf, acc_ctx, 0, 0, 0);
        }
      } else if (wid == 4 || wid == 6) {
        // q softmax over 32 channels for one pixel; store bf16 transposed [l][ck]
        int p = lane + ((wid == 6) ? 64 : 0);
        float qv[HC];
        float mx = -1e30f;
#pragma unroll
        for (int j = 0; j < HC; ++j) { qv[j] = qt[j][p]; mx = fmaxf(mx, qv[j]); }
        float ssum = 0.f;
#pragma unroll
        for (int j = 0; j < HC; ++j) { qv[j] = __expf(qv[j] - mx); ssum += qv[j]; }
        float inv = 1.f / ssum;
        size_t base = (((size_t)(n * NHEADS + h) * LSP + (size_t)(lb + p)) << 5);
#pragma unroll
        for (int jc = 0; jc < 4; ++jc) {
          short8 pk;
#pragma unroll
          for (int j = 0; j < 8; ++j) pk[j] = (short)f2bf(qv[jc * 8 + j] * inv);
          *(short8*)&qbuf[base + jc * 8] = pk;
        }
      } else if (wid == 5 && lane < HC) {
        // S partial: sum of bf16-rounded exp(k) (consistent with ctx MFMA operand)
        float s = 0.f;
#pragma unroll
        for (int pg = 0; pg < BN / 8; ++pg) {
          short8 e = *(const short8*)&ekt[lane][pg * 8];
#pragma unroll
          for (int j = 0; j < 8; ++j) s += bf2f((unsigned short)e[j]);
        }
        sk += s;
      }
    }
    // flush per-head accumulators (32 atomics/address-class total across grid)
    if (wid < 4) {
      int tm = wid >> 1, tn = wid & 1;
      float* cp = ctx + ((size_t)(n * NHEADS + h) * HC) * HC;
#pragma unroll
      for (int r = 0; r < 4; ++r) {
        int ck = tm * 16 + kg * 4 + r;
        int cv = tn * 16 + r16;
        atomicAdd(&cp[ck * HC + cv], acc_ctx[r]);
      }
    } else if (wid == 5 && lane < HC) {
      atomicAdd(&S[(n * NHEADS + h) * HC + lane], sk);
    }
  }
}

// ---------------- kernel 2: ctx/S, transpose, -> bf16 ----------------
__global__ void k_norm(const float* __restrict__ ctx, const float* __restrict__ S,
                       unsigned short* __restrict__ ctxT) {
  int idx = blockIdx.x * 256 + threadIdx.x;  // 65536 = [n][h][ck][cv]
  int cv = idx & 31, ck = (idx >> 5) & 31, nh = idx >> 10;
  float v = ctx[idx] / S[(nh << 5) + ck];
  ctxT[(nh << 10) + (cv << 5) + ck] = f2bf(v);
}

// ---------------- kernel 3: att = ctxT (32x32) x q_soft (32 x L) + residual ----------------
__global__ __launch_bounds__(256)
void k_att(const float* __restrict__ x, const unsigned short* __restrict__ qbuf,
           const unsigned short* __restrict__ ctxT, float* __restrict__ out) {
  int b = blockIdx.x;
  int lc = b & 63;           // 64 chunks of 256 pixels
  int nh = b >> 6;
  int h = nh & 7, n = nh >> 3;
  int tid = threadIdx.x, wid = tid >> 6, lane = tid & 63;
  int r16 = lane & 15, kg = lane >> 4;
  int lw = lc * 256 + wid * 64;

  const unsigned short* cp = ctxT + ((size_t)nh << 10);
  short8 a0 = *(const short8*)&cp[(r16 << 5) + kg * 8];          // A[cv][ck], cv 0-15
  short8 a1 = *(const short8*)&cp[((16 + r16) << 5) + kg * 8];   // cv 16-31
  const unsigned short* qb = qbuf + (((size_t)nh * LSP) << 5);
  const float* xp = x   + ((size_t)n * CCH + (size_t)h * HC) * LSP;
  float*       op = out + ((size_t)n * CCH + (size_t)h * HC) * LSP;

#pragma unroll
  for (int t = 0; t < 4; ++t) {
    int l = lw + t * 16;
    short8 bf = *(const short8*)&qb[((size_t)(l + r16) << 5) + kg * 8];  // B[ck][l]
    f32x4 d0 = {0, 0, 0, 0}, d1 = {0, 0, 0, 0};
    d0 = __builtin_amdgcn_mfma_f32_16x16x32_bf16(a0, bf, d0, 0, 0, 0);
    d1 = __builtin_amdgcn_mfma_f32_16x16x32_bf16(a1, bf, d1, 0, 0, 0);
#pragma unroll
    for (int r = 0; r < 4; ++r) {
      int cv = kg * 4 + r;
      int li = l + r16;
      op[(size_t)cv * LSP + li]        = d0[r] + xp[(size_t)cv * LSP + li];
      op[(size_t)(cv + 16) * LSP + li] = d1[r] + xp[(size_t)(cv + 16) * LSP + li];
    }
  }
}

extern "C" void kernel_launch(void* const* d_in, const int* in_sizes, int n_in,
                              void* d_out, int out_size, void* d_ws, size_t ws_size,
                              hipStream_t stream) {
  (void)in_sizes; (void)n_in; (void)out_size;
  const float* x  = (const float*)d_in[0];
  const float* Wk = (const float*)d_in[1];
  const float* bk = (const float*)d_in[2];
  const float* Wq = (const float*)d_in[3];
  const float* bq = (const float*)d_in[4];
  const float* Wv = (const float*)d_in[5];
  const float* bv = (const float*)d_in[6];
  float* out = (float*)d_out;

  // workspace layout (xT last so a small-ws fallback works without it)
  char* ws = (char*)d_ws;
  unsigned short* Wb   = (unsigned short*)(ws + 0);          //   393216
  float*          bbp  = (float*)(ws + 393216);              //     3072
  float*          ctx  = (float*)(ws + 396288);              //   262144
  unsigned short* ctxT = (unsigned short*)(ws + 658432);     //   131072
  float*          S    = (float*)(ws + 789504);              //     8192
  unsigned short* qbuf = (unsigned short*)(ws + 797696);     // 67108864
  unsigned short* xT   = (unsigned short*)(ws + 67906560);   // 67108864 -> 135015424 total
  bool use_xt = (ws_size >= 135015424ull);

  k_prep<<<768, 256, 0, stream>>>(Wk, bk, Wq, bq, Wv, bv, Wb, bbp, ctx, S);
  if (use_xt) {
    k_transpose<<<NB * 256 * 4, 256, 0, stream>>>(x, xT);
    k_qkv<true><<<256, 512, 0, stream>>>(x, xT, Wb, bbp, qbuf, ctx, S);
  } else {
    k_qkv<false><<<256, 512, 0, stream>>>(x, xT, Wb, bbp, qbuf, ctx, S);
  }
  k_norm<<<256, 256, 0, stream>>>(ctx, S, ctxT);
  k_att<<<NB * NHEADS * 64, 256, 0, stream>>>(x, qbuf, ctxT, out);
}